// Round 1
// baseline (129.485 us; speedup 1.0000x reference)
//
#include <hip/hip_runtime.h>

// Problem constants (fixed by the reference setup_inputs).
#define BATCH   2
#define DIMS    3
#define NPT     8192
#define CHUNK   512
#define THREADS 256
#define NCH     (NPT / CHUNK)   // 16 chunks per axis

// ---------------------------------------------------------------------------
// Kernel 1: all-pairs distance tiles; per-point running (min dist, argmin)
// merged across tiles via packed u64 atomicMin.
// Packing: (float_bits(dist) << 32) | index. dist >= 0 so float bits are
// monotone as u32; ties resolve to the smallest index (numpy argmin semantics).
// ---------------------------------------------------------------------------
__global__ __launch_bounds__(THREADS) void dacd_pair_kernel(
    const float* __restrict__ x, const float* __restrict__ gt,
    unsigned long long* __restrict__ best1,   // [BATCH*NPT] x -> nearest gt
    unsigned long long* __restrict__ best2)   // [BATCH*NPT] gt -> nearest x
{
    __shared__ float4 sx[CHUNK];
    __shared__ float4 sg[CHUNK];

    const int blk = blockIdx.x;
    const int b   = blk / (NCH * NCH);
    const int rem = blk % (NCH * NCH);
    const int ci  = rem / NCH;           // x chunk
    const int cj  = rem % NCH;           // gt chunk
    const int n0  = ci * CHUNK;
    const int m0  = cj * CHUNK;
    const float* xb = x  + b * (DIMS * NPT);
    const float* gb = gt + b * (DIMS * NPT);
    const int t = threadIdx.x;

    // Stage both chunks (coalesced per-dim loads, float4-padded LDS rows).
    for (int i = t; i < CHUNK; i += THREADS) {
        sx[i] = make_float4(xb[n0 + i], xb[NPT + n0 + i], xb[2 * NPT + n0 + i], 0.0f);
        sg[i] = make_float4(gb[m0 + i], gb[NPT + m0 + i], gb[2 * NPT + m0 + i], 0.0f);
    }
    __syncthreads();

    // Direction 1: this block's x points vs gt chunk (2 points / thread).
    {
        const float4 p0 = sx[t];
        const float4 p1 = sx[t + THREADS];
        float bd0 = INFINITY, bd1 = INFINITY;
        int   bi0 = 0,        bi1 = 0;
        #pragma unroll 4
        for (int j = 0; j < CHUNK; ++j) {
            const float4 g = sg[j];          // wave-uniform -> LDS broadcast
            float dx0 = p0.x - g.x, dy0 = p0.y - g.y, dz0 = p0.z - g.z;
            float d0  = dx0 * dx0 + dy0 * dy0 + dz0 * dz0;
            float dx1 = p1.x - g.x, dy1 = p1.y - g.y, dz1 = p1.z - g.z;
            float d1  = dx1 * dx1 + dy1 * dy1 + dz1 * dz1;
            if (d0 < bd0) { bd0 = d0; bi0 = j; }
            if (d1 < bd1) { bd1 = d1; bi1 = j; }
        }
        unsigned long long pk0 =
            ((unsigned long long)__float_as_uint(bd0) << 32) | (unsigned)(m0 + bi0);
        unsigned long long pk1 =
            ((unsigned long long)__float_as_uint(bd1) << 32) | (unsigned)(m0 + bi1);
        atomicMin(&best1[b * NPT + n0 + t],           pk0);
        atomicMin(&best1[b * NPT + n0 + t + THREADS], pk1);
    }

    // Direction 2: this block's gt points vs x chunk (2 points / thread).
    {
        const float4 p0 = sg[t];
        const float4 p1 = sg[t + THREADS];
        float bd0 = INFINITY, bd1 = INFINITY;
        int   bi0 = 0,        bi1 = 0;
        #pragma unroll 4
        for (int j = 0; j < CHUNK; ++j) {
            const float4 g = sx[j];
            float dx0 = p0.x - g.x, dy0 = p0.y - g.y, dz0 = p0.z - g.z;
            float d0  = dx0 * dx0 + dy0 * dy0 + dz0 * dz0;
            float dx1 = p1.x - g.x, dy1 = p1.y - g.y, dz1 = p1.z - g.z;
            float d1  = dx1 * dx1 + dy1 * dy1 + dz1 * dz1;
            if (d0 < bd0) { bd0 = d0; bi0 = j; }
            if (d1 < bd1) { bd1 = d1; bi1 = j; }
        }
        unsigned long long pk0 =
            ((unsigned long long)__float_as_uint(bd0) << 32) | (unsigned)(n0 + bi0);
        unsigned long long pk1 =
            ((unsigned long long)__float_as_uint(bd1) << 32) | (unsigned)(n0 + bi1);
        atomicMin(&best2[b * NPT + m0 + t],           pk0);
        atomicMin(&best2[b * NPT + m0 + t + THREADS], pk1);
    }
}

// ---------------------------------------------------------------------------
// Kernel 2: NN-index histograms.
// ---------------------------------------------------------------------------
__global__ __launch_bounds__(256) void dacd_count_kernel(
    const unsigned long long* __restrict__ best1,
    const unsigned long long* __restrict__ best2,
    int* __restrict__ count1, int* __restrict__ count2)
{
    const int i = blockIdx.x * 256 + threadIdx.x;   // over BATCH*NPT
    const int b = i / NPT;
    const unsigned j1 = (unsigned)best1[i];
    atomicAdd(&count1[b * NPT + j1], 1);
    const unsigned j2 = (unsigned)best2[i];
    atomicAdd(&count2[b * NPT + j2], 1);
}

// ---------------------------------------------------------------------------
// Kernel 3: weighted loss contributions, block-reduced into a double accum.
// frac_12 = frac_21 = 1.0 since N == M.
// ---------------------------------------------------------------------------
__global__ __launch_bounds__(256) void dacd_loss_kernel(
    const unsigned long long* __restrict__ best1,
    const unsigned long long* __restrict__ best2,
    const int* __restrict__ count1, const int* __restrict__ count2,
    double* __restrict__ acc)
{
    const int i = blockIdx.x * 256 + threadIdx.x;
    const int b = i / NPT;

    const unsigned long long p1 = best1[i];
    const float d1 = __uint_as_float((unsigned)(p1 >> 32));
    const unsigned j1 = (unsigned)p1;
    const float w1 = 1.0f / ((float)count1[b * NPT + j1] + 1e-6f);
    const float c1 = 1.0f - expf(-10.0f * d1) * w1;

    const unsigned long long p2 = best2[i];
    const float d2 = __uint_as_float((unsigned)(p2 >> 32));
    const unsigned j2 = (unsigned)p2;
    const float w2 = 1.0f / ((float)count2[b * NPT + j2] + 1e-6f);
    const float c2 = 1.0f - expf(-10.0f * d2) * w2;

    double v = (double)c1 + (double)c2;
    // wave-64 butterfly reduce
    #pragma unroll
    for (int off = 32; off > 0; off >>= 1)
        v += __shfl_down(v, off, 64);

    __shared__ double wsum[4];
    const int lane = threadIdx.x & 63, wid = threadIdx.x >> 6;
    if (lane == 0) wsum[wid] = v;
    __syncthreads();
    if (threadIdx.x == 0) {
        atomicAdd(acc, wsum[0] + wsum[1] + wsum[2] + wsum[3]);
    }
}

__global__ void dacd_final_kernel(const double* __restrict__ acc,
                                  float* __restrict__ out)
{
    if (threadIdx.x == 0 && blockIdx.x == 0) {
        // loss = sum / (2 * B * N)   (mean over b of (loss1+loss2)/2)
        out[0] = (float)(acc[0] * (1.0 / (2.0 * BATCH * NPT)));
    }
}

extern "C" void kernel_launch(void* const* d_in, const int* in_sizes, int n_in,
                              void* d_out, int out_size, void* d_ws, size_t ws_size,
                              hipStream_t stream)
{
    const float* x  = (const float*)d_in[0];
    const float* gt = (const float*)d_in[1];
    float* out = (float*)d_out;

    // Workspace layout (all offsets 8B-aligned):
    //   best1 [B*N] u64 | best2 [B*N] u64 | count1 [B*N] i32 | count2 [B*N] i32 | acc f64
    char* ws = (char*)d_ws;
    unsigned long long* best1 = (unsigned long long*)ws;
    unsigned long long* best2 = best1 + BATCH * NPT;
    int* count1 = (int*)(best2 + BATCH * NPT);
    int* count2 = count1 + BATCH * NPT;
    double* acc = (double*)(count2 + BATCH * NPT);

    const size_t bestBytes = (size_t)2 * BATCH * NPT * sizeof(unsigned long long);
    const size_t zeroBytes = (size_t)2 * BATCH * NPT * sizeof(int) + sizeof(double);
    hipMemsetAsync(best1, 0xFF, bestBytes, stream);   // packed +inf sentinels
    hipMemsetAsync(count1, 0, zeroBytes, stream);     // counts + accumulator

    dacd_pair_kernel<<<BATCH * NCH * NCH, THREADS, 0, stream>>>(x, gt, best1, best2);
    dacd_count_kernel<<<(BATCH * NPT) / 256, 256, 0, stream>>>(best1, best2, count1, count2);
    dacd_loss_kernel<<<(BATCH * NPT) / 256, 256, 0, stream>>>(best1, best2, count1, count2, acc);
    dacd_final_kernel<<<1, 64, 0, stream>>>(acc, out);
}

// Round 2
// 121.363 us; speedup vs baseline: 1.0669x; 1.0669x over previous
//
#include <hip/hip_runtime.h>

// Problem constants (fixed by the reference setup_inputs).
#define BATCH   2
#define NPT     8192
#define THREADS 256
#define PPT     8                    // own points per thread
#define OWN     (THREADS * PPT)      // 2048 own points per block
#define OPP     256                  // opposing points staged in LDS
#define NCI     (NPT / OWN)          // 4 own chunks
#define NCJ     (NPT / OPP)          // 32 opp chunks
// grid = 2 dirs * BATCH * NCI * NCJ = 512 blocks

typedef unsigned long long u64;

// ---------------------------------------------------------------------------
// Pair kernel. Each block: one direction, one batch, own-chunk of 2048 points
// (8/thread, in registers), loops over one 256-point opposing chunk in LDS.
// Tracks min over j of m = |g|^2 - 2*p.g  (equivalent argmin to squared L2,
// since d = |p|^2 + m with |p|^2 constant per point). Reconstructs d at the
// end and merges across opp-chunks via atomicMax of ~((bits(d)<<32)|j),
// which == atomicMin of (d, j) lexicographic and works with 0-initialized
// memory (no 0xFF memset node needed).
// ---------------------------------------------------------------------------
__global__ __launch_bounds__(THREADS) void dacd_pair_kernel(
    const float* __restrict__ x, const float* __restrict__ gt,
    u64* __restrict__ bestAll)       // [2][BATCH*NPT], holds ~packed
{
    __shared__ float4 sg[OPP];       // (gx, gy, gz, |g|^2)

    const int id  = blockIdx.x;
    const int dir = id & 1;
    const int b   = (id >> 1) & 1;
    const int ci  = (id >> 2) & (NCI - 1);
    const int cj  = id >> 4;                    // 0..NCJ-1

    const float* own = dir == 0 ? x : gt;
    const float* opp = dir == 0 ? gt : x;
    u64* best = bestAll + (size_t)dir * (BATCH * NPT) + (size_t)b * NPT;

    const int t = threadIdx.x;
    const float* ob = own + (size_t)b * (3 * NPT);
    const float* pb = opp + (size_t)b * (3 * NPT);

    // Stage opposing chunk (one point per thread), with |g|^2 precomputed.
    {
        const int j = cj * OPP + t;
        const float gx = pb[j], gy = pb[NPT + j], gz = pb[2 * NPT + j];
        sg[t] = make_float4(gx, gy, gz, fmaf(gx, gx, fmaf(gy, gy, gz * gz)));
    }

    // Own points into registers.
    float px[PPT], py[PPT], pz[PPT], bm[PPT];
    int   bj[PPT];
    const int i0 = ci * OWN + t;
    #pragma unroll
    for (int p = 0; p < PPT; ++p) {
        const int i = i0 + p * THREADS;
        px[p] = ob[i];
        py[p] = ob[NPT + i];
        pz[p] = ob[2 * NPT + i];
        bm[p] = INFINITY;
        bj[p] = 0;
    }
    __syncthreads();

    #pragma unroll 2
    for (int j = 0; j < OPP; ++j) {
        const float4 g = sg[j];      // wave-uniform ds_read_b128
        #pragma unroll
        for (int p = 0; p < PPT; ++p) {
            const float dot = fmaf(px[p], g.x, fmaf(py[p], g.y, pz[p] * g.z));
            const float m   = fmaf(-2.0f, dot, g.w);
            if (m < bm[p]) { bm[p] = m; bj[p] = j; }
        }
    }

    // Reconstruct true squared distance and merge across chunks.
    #pragma unroll
    for (int p = 0; p < PPT; ++p) {
        const float xx = fmaf(px[p], px[p], fmaf(py[p], py[p], pz[p] * pz[p]));
        const float d  = fmaxf(xx + bm[p], 0.0f);
        const u64 pk = ((u64)__float_as_uint(d) << 32) | (unsigned)(cj * OPP + bj[p]);
        atomicMax(&best[i0 + p * THREADS], ~pk);
    }
}

// ---------------------------------------------------------------------------
// Histogram of NN indices (both directions). counts were zeroed by memset.
// ---------------------------------------------------------------------------
__global__ __launch_bounds__(256) void dacd_count_kernel(
    const u64* __restrict__ bestAll, int* __restrict__ countAll)
{
    const int i = blockIdx.x * 256 + threadIdx.x;   // 0 .. BATCH*NPT-1
    const int b = i >> 13;                          // i / NPT
    const unsigned j1 = (unsigned)(~bestAll[i]);
    atomicAdd(&countAll[(b << 13) | j1], 1);
    const unsigned j2 = (unsigned)(~bestAll[BATCH * NPT + i]);
    atomicAdd(&countAll[BATCH * NPT + ((b << 13) | j2)], 1);
}

// ---------------------------------------------------------------------------
// Loss: single block, 1024 threads; everything is L2-hot (~400 KB reads).
// loss = sum over all 2*B*N terms / (2*B*N).
// ---------------------------------------------------------------------------
__global__ __launch_bounds__(1024) void dacd_loss_kernel(
    const u64* __restrict__ bestAll, const int* __restrict__ countAll,
    float* __restrict__ out)
{
    const int t = threadIdx.x;
    double local = 0.0;
    for (int k = t; k < 2 * BATCH * NPT; k += 1024) {
        const u64 v = ~bestAll[k];
        const float d = __uint_as_float((unsigned)(v >> 32));
        const unsigned j = (unsigned)v;
        const int dirb = k >> 13;                    // dir*BATCH + b, 0..3
        const int cnt = countAll[(dirb << 13) | j];
        const float w = 1.0f / ((float)cnt + 1e-6f);
        local += (double)(1.0f - expf(-10.0f * d) * w);
    }
    // wave reduce
    #pragma unroll
    for (int off = 32; off > 0; off >>= 1)
        local += __shfl_down(local, off, 64);
    __shared__ double red[16];
    const int lane = t & 63, wid = t >> 6;
    if (lane == 0) red[wid] = local;
    __syncthreads();
    if (t == 0) {
        double s = 0.0;
        #pragma unroll
        for (int w = 0; w < 16; ++w) s += red[w];
        out[0] = (float)(s * (1.0 / (2.0 * BATCH * NPT)));
    }
}

extern "C" void kernel_launch(void* const* d_in, const int* in_sizes, int n_in,
                              void* d_out, int out_size, void* d_ws, size_t ws_size,
                              hipStream_t stream)
{
    const float* x  = (const float*)d_in[0];
    const float* gt = (const float*)d_in[1];
    float* out = (float*)d_out;

    // ws layout: bestAll [2][B*N] u64 | countAll [2][B*N] i32
    u64* bestAll  = (u64*)d_ws;
    int* countAll = (int*)(bestAll + 2 * BATCH * NPT);

    const size_t zeroBytes = (size_t)2 * BATCH * NPT * (sizeof(u64) + sizeof(int));
    hipMemsetAsync(bestAll, 0, zeroBytes, stream);

    dacd_pair_kernel<<<2 * BATCH * NCI * NCJ, THREADS, 0, stream>>>(x, gt, bestAll);
    dacd_count_kernel<<<(BATCH * NPT) / 256, 256, 0, stream>>>(bestAll, countAll);
    dacd_loss_kernel<<<1, 1024, 0, stream>>>(bestAll, countAll, out);
}

// Round 3
// 93.720 us; speedup vs baseline: 1.3816x; 1.2949x over previous
//
#include <hip/hip_runtime.h>

// Problem constants (fixed by the reference setup_inputs).
#define BATCH   2
#define NPT     8192
#define THREADS 256
#define PPT     8                    // own points per thread
#define OWN     (THREADS * PPT)      // 2048 own points per block
#define OPP     128                  // opposing points staged in LDS
#define NCI     (NPT / OWN)          // 4 own chunks
#define NCJ     (NPT / OPP)          // 64 opp chunks
// grid = 2 dirs * BATCH * NCI * NCJ = 1024 blocks -> 4 blocks/CU, 16 waves/CU

typedef unsigned long long u64;

// ---------------------------------------------------------------------------
// Pair kernel. Block: one (dir, batch, own-chunk of 2048, opp-chunk of 128).
// Own points in registers (8/thread); opp chunk staged in LDS pre-scaled as
// h = (-2gx, -2gy, -2gz, |g|^2) so the per-pair kernel is exactly
//   m = fma(px,hx, fma(py,hy, fma(pz,hz, hw)))   (3 fma)
//   min/argmin update                             (cmp + 2 cndmask)
// d = |p|^2 + min(m) is reconstructed once per point at the end and merged
// across opp-chunks via atomicMax(~((bits(d)<<32)|j)) == lexicographic
// atomicMin(d, j), correct with 0-initialized memory.
// ---------------------------------------------------------------------------
__global__ __launch_bounds__(THREADS) void dacd_pair_kernel(
    const float* __restrict__ x, const float* __restrict__ gt,
    u64* __restrict__ bestAll)       // [2][BATCH*NPT], holds ~packed
{
    __shared__ float4 sg[OPP];

    const int id  = blockIdx.x;
    const int dir = id & 1;
    const int b   = (id >> 1) & 1;
    const int ci  = (id >> 2) & (NCI - 1);
    const int cj  = id >> 4;                    // 0..NCJ-1

    const float* own = dir == 0 ? x : gt;
    const float* opp = dir == 0 ? gt : x;
    u64* best = bestAll + (size_t)dir * (BATCH * NPT) + (size_t)b * NPT;

    const int t = threadIdx.x;
    const float* ob = own + (size_t)b * (3 * NPT);
    const float* pb = opp + (size_t)b * (3 * NPT);

    // Stage opp chunk, pre-scaled, with |g|^2 in .w.
    if (t < OPP) {
        const int j = cj * OPP + t;
        const float gx = pb[j], gy = pb[NPT + j], gz = pb[2 * NPT + j];
        sg[t] = make_float4(-2.0f * gx, -2.0f * gy, -2.0f * gz,
                            fmaf(gx, gx, fmaf(gy, gy, gz * gz)));
    }

    // Own points into registers.
    float px[PPT], py[PPT], pz[PPT], bm[PPT];
    int   bj[PPT];
    const int i0 = ci * OWN + t;
    #pragma unroll
    for (int p = 0; p < PPT; ++p) {
        const int i = i0 + p * THREADS;
        px[p] = ob[i];
        py[p] = ob[NPT + i];
        pz[p] = ob[2 * NPT + i];
        bm[p] = INFINITY;
        bj[p] = 0;
    }
    __syncthreads();

    #pragma unroll 4
    for (int j = 0; j < OPP; ++j) {
        const float4 h = sg[j];      // wave-uniform ds_read_b128 (broadcast)
        #pragma unroll
        for (int p = 0; p < PPT; ++p) {
            const float m = fmaf(px[p], h.x, fmaf(py[p], h.y, fmaf(pz[p], h.z, h.w)));
            if (m < bm[p]) { bm[p] = m; bj[p] = j; }
        }
    }

    // Reconstruct true squared distance and merge across chunks.
    #pragma unroll
    for (int p = 0; p < PPT; ++p) {
        const float pp = fmaf(px[p], px[p], fmaf(py[p], py[p], pz[p] * pz[p]));
        const float d  = fmaxf(pp + bm[p], 0.0f);
        const u64 pk = ((u64)__float_as_uint(d) << 32) | (unsigned)(cj * OPP + bj[p]);
        atomicMax(&best[i0 + p * THREADS], ~pk);
    }
}

// ---------------------------------------------------------------------------
// Histogram of NN indices (both directions). counts zeroed by memset.
// ---------------------------------------------------------------------------
__global__ __launch_bounds__(256) void dacd_count_kernel(
    const u64* __restrict__ bestAll, int* __restrict__ countAll)
{
    const int i = blockIdx.x * 256 + threadIdx.x;   // 0 .. BATCH*NPT-1
    const int b = i >> 13;                          // i / NPT
    const unsigned j1 = (unsigned)(~bestAll[i]);
    atomicAdd(&countAll[(b << 13) | j1], 1);
    const unsigned j2 = (unsigned)(~bestAll[BATCH * NPT + i]);
    atomicAdd(&countAll[BATCH * NPT + ((b << 13) | j2)], 1);
}

// ---------------------------------------------------------------------------
// Loss + finalize: 64 blocks; per-block f64 partial -> atomicAdd(acc);
// ticket: last block reads acc and writes the scalar output.
// ---------------------------------------------------------------------------
#define LGRID 64
__global__ __launch_bounds__(256) void dacd_loss_kernel(
    const u64* __restrict__ bestAll, const int* __restrict__ countAll,
    double* __restrict__ acc, unsigned* __restrict__ ticket,
    float* __restrict__ out)
{
    const int t = threadIdx.x;
    double local = 0.0;
    #pragma unroll
    for (int q = 0; q < 2; ++q) {
        const int k = (blockIdx.x * 512) + q * 256 + t;   // 0 .. 32767
        const u64 v = ~bestAll[k];
        const float d = __uint_as_float((unsigned)(v >> 32));
        const unsigned j = (unsigned)v;
        const int dirb = k >> 13;                         // dir*BATCH+b, 0..3
        const int cnt = countAll[(dirb << 13) | j];
        const float w = 1.0f / ((float)cnt + 1e-6f);
        local += (double)(1.0f - expf(-10.0f * d) * w);
    }
    #pragma unroll
    for (int off = 32; off > 0; off >>= 1)
        local += __shfl_down(local, off, 64);
    __shared__ double red[4];
    const int lane = t & 63, wid = t >> 6;
    if (lane == 0) red[wid] = local;
    __syncthreads();
    if (t == 0) {
        atomicAdd(acc, red[0] + red[1] + red[2] + red[3]);
        __threadfence();
        const unsigned old = atomicAdd(ticket, 1u);
        if (old == LGRID - 1) {
            __threadfence();
            const double s = atomicAdd(acc, 0.0);         // coherent read
            out[0] = (float)(s * (1.0 / (2.0 * BATCH * NPT)));
        }
    }
}

extern "C" void kernel_launch(void* const* d_in, const int* in_sizes, int n_in,
                              void* d_out, int out_size, void* d_ws, size_t ws_size,
                              hipStream_t stream)
{
    const float* x  = (const float*)d_in[0];
    const float* gt = (const float*)d_in[1];
    float* out = (float*)d_out;

    // ws layout: bestAll [2][B*N] u64 | countAll [2][B*N] i32 | acc f64 | ticket u32
    u64* bestAll  = (u64*)d_ws;
    int* countAll = (int*)(bestAll + 2 * BATCH * NPT);
    double* acc   = (double*)(countAll + 2 * BATCH * NPT);
    unsigned* ticket = (unsigned*)(acc + 1);

    const size_t zeroBytes =
        (size_t)2 * BATCH * NPT * (sizeof(u64) + sizeof(int)) + sizeof(double) + 2 * sizeof(unsigned);
    hipMemsetAsync(bestAll, 0, zeroBytes, stream);

    dacd_pair_kernel<<<2 * BATCH * NCI * NCJ, THREADS, 0, stream>>>(x, gt, bestAll);
    dacd_count_kernel<<<(BATCH * NPT) / 256, 256, 0, stream>>>(bestAll, countAll);
    dacd_loss_kernel<<<LGRID, 256, 0, stream>>>(bestAll, countAll, acc, ticket, out);
}